// Round 5
// baseline (93.074 us; speedup 1.0000x reference)
//
#include <hip/hip_runtime.h>
#include <hip/hip_bf16.h>

#define NBATCH 8
#define BROWS 256
#define KDIM 512
#define HIDD 512
#define GDIM 2048
#define KSTEP 64
#define NIT (KDIM / KSTEP)

typedef float f32x4 __attribute__((ext_vector_type(4)));
typedef float f32x16 __attribute__((ext_vector_type(16)));
typedef __bf16 bf16x8 __attribute__((ext_vector_type(8)));

__device__ __forceinline__ unsigned fenc(float f) {
    unsigned u = __float_as_uint(f);
    return (u & 0x80000000u) ? ~u : (u | 0x80000000u);
}
__device__ __forceinline__ float fdec(unsigned e) {
    unsigned u = (e & 0x80000000u) ? (e & 0x7fffffffu) : ~e;
    return __uint_as_float(u);
}
__device__ __forceinline__ unsigned umaxu(unsigned a, unsigned b) { return a > b ? a : b; }

// quant(pact(x,a), 8, a)  -- all a's are powers of 2 so /a, *a are exact
__device__ __forceinline__ float qpact(float x, float a) {
    float ax = fabsf(x);
    float p  = copysignf(0.5f * (ax - fabsf(ax - a) + a), x);
    float x01 = p / a;
    x01 = fminf(fmaxf(x01, -0.9921875f), 0.9921875f);
    return (rintf(x01 * 128.f) * 0.0078125f) * a;
}
// quant(x, 8, 1.0)
__device__ __forceinline__ float q1(float x) {
    float x01 = fminf(fmaxf(x, -0.9921875f), 0.9921875f);
    return rintf(x01 * 128.f) * 0.0078125f;
}
__device__ __forceinline__ float sigmf(float x) { return 1.0f / (1.0f + expf(-x)); }

__global__ void k_max(const float* __restrict__ w_ih, const float* __restrict__ w_hh,
                      const float* __restrict__ b_ih, const float* __restrict__ b_hh,
                      unsigned* __restrict__ omax) {
    int which = blockIdx.y;
    const float* src = which == 0 ? w_ih : which == 1 ? w_hh : which == 2 ? b_ih : b_hh;
    int n4 = (which < 2 ? NBATCH * KDIM * GDIM : NBATCH * GDIM) >> 2;
    unsigned best = 0u;
    int stride = gridDim.x * blockDim.x;
    for (int i = blockIdx.x * blockDim.x + threadIdx.x; i < n4; i += stride) {
        float4 v = ((const float4*)src)[i];
        best = umaxu(best, fenc(v.x)); best = umaxu(best, fenc(v.y));
        best = umaxu(best, fenc(v.z)); best = umaxu(best, fenc(v.w));
    }
    #pragma unroll
    for (int off = 32; off > 0; off >>= 1)
        best = umaxu(best, (unsigned)__shfl_down((int)best, off, 64));
    __shared__ unsigned red[4];
    int lane = threadIdx.x & 63, wv = threadIdx.x >> 6;
    if (lane == 0) red[wv] = best;
    __syncthreads();
    if (threadIdx.x == 0) {
        unsigned b2 = umaxu(umaxu(red[0], red[1]), umaxu(red[2], red[3]));
        atomicMax(&omax[which], b2);
    }
}

__global__ void k_prep(const float* __restrict__ input, const float* __restrict__ hx,
                       const float* __restrict__ bih, const float* __restrict__ bhh,
                       const float* __restrict__ nbih, const float* __restrict__ nbhh,
                       const float* __restrict__ a1, const unsigned* __restrict__ maxes,
                       __hip_bfloat16* __restrict__ xqh, __hip_bfloat16* __restrict__ hxh,
                       __hip_bfloat16* __restrict__ hxl, float* __restrict__ bias_comb) {
    const int NX = NBATCH * BROWS * KDIM;
    const int NH = NBATCH * BROWS * HIDD;
    const int NBC = NBATCH * GDIM;
    int total = NX + NH + NBC;
    int stride = gridDim.x * blockDim.x;
    for (int i = blockIdx.x * blockDim.x + threadIdx.x; i < total; i += stride) {
        if (i < NX) {
            int nb = i >> 17;              // /(256*512)
            int rem = i & 131071;
            float v = qpact(input[rem], a1[nb]);
            xqh[i] = __float2bfloat16(v);  // exact: integers <=127 for a1=128
        } else if (i < NX + NH) {
            int j = i - NX;
            float h = hx[j];
            __hip_bfloat16 hi = __float2bfloat16(h);
            hxh[j] = hi;
            hxl[j] = __float2bfloat16(h - __bfloat162float(hi));
        } else {
            int j = i - NX - NH;
            float mb_ih = fdec(maxes[2]);
            float mb_hh = fdec(maxes[3]);
            bias_comb[j] = q1(bih[j]) + (nbih[j] * mb_ih) * 0.05f
                         + q1(bhh[j]) + (nbhh[j] * mb_hh) * 0.05f;
        }
    }
}

// producer/consumer k_gemm: waves 0-7 = MFMA consumers (32 rows each, 32x32x16),
// waves 8-15 = staging producers (load w,z -> quant+split -> LDS).
__global__ __launch_bounds__(1024, 1) void k_gemm(
    const float* __restrict__ w_ih, const float* __restrict__ w_hh,
    const float* __restrict__ n_ih, const float* __restrict__ n_hh,
    const __hip_bfloat16* __restrict__ xqh, const __hip_bfloat16* __restrict__ hxh,
    const __hip_bfloat16* __restrict__ hxl,
    const float* __restrict__ bias_comb, const float* __restrict__ cx,
    const float* __restrict__ a3, const float* __restrict__ a4, const float* __restrict__ a5,
    const float* __restrict__ a6, const float* __restrict__ a7, const float* __restrict__ a8,
    const float* __restrict__ a9, const float* __restrict__ a10, const float* __restrict__ a11,
    const unsigned* __restrict__ maxes,
    float* __restrict__ out_h, float* __restrict__ out_c)
{
    // [buf][mat][n=64][k=64 pad 72] bf16 -> 72 KB
    // col slots n: 0-15 gate i, 16-31 gate f, 32-47 gate j, 48-63 gate o
    __shared__ __hip_bfloat16 Bsm[2][4][64][72];

    int tid = threadIdx.x;
    int lane = tid & 63, wv = tid >> 6;          // 16 waves
    int nb = blockIdx.x & 7;
    int cb = blockIdx.x >> 3;                    // 32 col-blocks of 16 HID cols

    const float* wih_b = w_ih + nb * KDIM * GDIM;
    const float* whh_b = w_hh + nb * KDIM * GDIM;
    const float* nih_b = n_ih + nb * KDIM * GDIM;
    const float* nhh_b = n_hh + nb * KDIM * GDIM;
    const __hip_bfloat16* xq_b = xqh + nb * BROWS * KDIM;
    const __hip_bfloat16* hh_b = hxh + nb * BROWS * KDIM;
    const __hip_bfloat16* hl_b = hxl + nb * BROWS * KDIM;

    float c_ih = fdec(maxes[0]);
    float c_hh = fdec(maxes[1]);

    bool producer = wv >= 8;

    // ---- producer mapping: col-slot pn = lane, k-octet po = wv-8 ----
    int pn = lane;
    int po = (wv - 8) & 7;
    int ps = pn >> 4;
    int gm = (int)((0x3120u >> (ps << 2)) & 0xFu);      // slot->gate {0,2,1,3}
    int pcol = (gm << 9) + (cb << 4) + (pn & 15);

    // ---- consumer mapping ----
    int cw = wv & 7;                 // row-band (rows 32*cw .. +31)
    int c31 = lane & 31;
    int ck8 = (lane >> 5) << 3;      // k sub-octet 0/8

    f32x16 acc0 = {}, acc1 = {};     // col-groups [i|f] and [j|o]
    float rw1[8], rz1[8], rw2[8], rz2[8];

#define PSTAGE(K0) {                                         \
    int kb = (K0) + (po << 3);                               \
    _Pragma("unroll")                                        \
    for (int j = 0; j < 8; ++j) {                            \
        int gx = (kb + j) * GDIM + pcol;                     \
        rw1[j] = wih_b[gx]; rz1[j] = nih_b[gx];              \
        rw2[j] = whh_b[gx]; rz2[j] = nhh_b[gx];              \
    } }

#define PCVT1(P, RW, RZ, CM, MHI) {                          \
    bf16x8 hi8, lo8;                                         \
    _Pragma("unroll")                                        \
    for (int j = 0; j < 8; ++j) {                            \
        float w = RW[j];                                     \
        float wq = rintf(fminf(fmaxf(w, -0.9921875f), 0.9921875f) * 128.f) * 0.0078125f; \
        float e = wq + (RZ[j] * (CM)) * 0.05f;               \
        __hip_bfloat16 h = __float2bfloat16(e);              \
        float lof = e - __bfloat162float(h);                 \
        __hip_bfloat16 lb = __float2bfloat16(lof);           \
        hi8[j] = *reinterpret_cast<__bf16*>(&h);             \
        lo8[j] = *reinterpret_cast<__bf16*>(&lb);            \
    }                                                        \
    *(bf16x8*)&Bsm[P][MHI][pn][po << 3] = hi8;               \
    *(bf16x8*)&Bsm[P][(MHI) + 1][pn][po << 3] = lo8; }

#define MFMA5(ACC, AX, AH, AL, B0, B1, B2, B3)                                \
    ACC = __builtin_amdgcn_mfma_f32_32x32x16_bf16(AX, B0, ACC, 0, 0, 0);      \
    ACC = __builtin_amdgcn_mfma_f32_32x32x16_bf16(AX, B1, ACC, 0, 0, 0);      \
    ACC = __builtin_amdgcn_mfma_f32_32x32x16_bf16(AH, B2, ACC, 0, 0, 0);      \
    ACC = __builtin_amdgcn_mfma_f32_32x32x16_bf16(AH, B3, ACC, 0, 0, 0);      \
    ACC = __builtin_amdgcn_mfma_f32_32x32x16_bf16(AL, B2, ACC, 0, 0, 0);

    if (producer) PSTAGE(0);

    for (int ph = 0; ph <= NIT; ++ph) {
        if (producer) {
            if (ph < NIT) {
                int P = ph & 1;
                PCVT1(P, rw1, rz1, c_ih, 0);
                PCVT1(P, rw2, rz2, c_hh, 2);
                if (ph + 1 < NIT) PSTAGE((ph + 1) * KSTEP);
            }
        } else if (ph > 0) {
            int K0 = (ph - 1) * KSTEP;
            int P = (ph - 1) & 1;
            bf16x8 ax[4], ah[4], al[4];
            int abase = (cw * 32 + c31) * KDIM + K0 + ck8;
            #pragma unroll
            for (int kc = 0; kc < 4; ++kc) {
                ax[kc] = *(const bf16x8*)(xq_b + abase + kc * 16);
                ah[kc] = *(const bf16x8*)(hh_b + abase + kc * 16);
                al[kc] = *(const bf16x8*)(hl_b + abase + kc * 16);
            }
            #pragma unroll
            for (int kc = 0; kc < 4; ++kc) {
                int kb = kc * 16 + ck8;
                {
                    bf16x8 b0 = *(const bf16x8*)&Bsm[P][0][c31][kb];
                    bf16x8 b1 = *(const bf16x8*)&Bsm[P][1][c31][kb];
                    bf16x8 b2 = *(const bf16x8*)&Bsm[P][2][c31][kb];
                    bf16x8 b3 = *(const bf16x8*)&Bsm[P][3][c31][kb];
                    MFMA5(acc0, ax[kc], ah[kc], al[kc], b0, b1, b2, b3);
                }
                {
                    bf16x8 b0 = *(const bf16x8*)&Bsm[P][0][32 + c31][kb];
                    bf16x8 b1 = *(const bf16x8*)&Bsm[P][1][32 + c31][kb];
                    bf16x8 b2 = *(const bf16x8*)&Bsm[P][2][32 + c31][kb];
                    bf16x8 b3 = *(const bf16x8*)&Bsm[P][3][32 + c31][kb];
                    MFMA5(acc1, ax[kc], ah[kc], al[kc], b0, b1, b2, b3);
                }
            }
        }
        __syncthreads();
    }

    if (!producer) {
        // exchange across lane^16: partner holds the other two gates for same hcol
        float recv0[16], recv1[16];
        #pragma unroll
        for (int r = 0; r < 16; ++r) {
            recv0[r] = __shfl_xor(acc0[r], 16);
            recv1[r] = __shfl_xor(acc1[r], 16);
        }
        int hcol = (cb << 4) + (lane & 15);
        int hi = (lane >> 4) & 1;
        float A3 = a3[nb], A4 = a4[nb], A5 = a5[nb], A6 = a6[nb], A7 = a7[nb];
        float A8 = a8[nb], A9 = a9[nb], A10 = a10[nb], A11 = a11[nb];
        float bc_i = bias_comb[nb * GDIM + hcol];
        float bc_j = bias_comb[nb * GDIM + 512 + hcol];
        float bc_f = bias_comb[nb * GDIM + 1024 + hcol];
        float bc_o = bias_comb[nb * GDIM + 1536 + hcol];
        int rbase = 16 * hi + 4 * (lane >> 5);
        #pragma unroll
        for (int r = 0; r < 8; ++r) {
            float a0s = hi ? acc0[r + 8] : acc0[r];
            float a1s = hi ? acc1[r + 8] : acc1[r];
            float r0s = hi ? recv0[r + 8] : recv0[r];
            float r1s = hi ? recv1[r + 8] : recv1[r];
            float gi = (hi ? r0s : a0s) + bc_i;
            float gj = (hi ? r1s : a1s) + bc_j;
            float gf = (hi ? a0s : r0s) + bc_f;
            float go = (hi ? a1s : r1s) + bc_o;
            int row = cw * 32 + rbase + (r & 3) + 8 * (r >> 2);
            float fg = qpact(sigmf(gf), A3);
            float ig = qpact(sigmf(gi), A4);
            float act = qpact(tanhf(gj), A5);
            float og = qpact(sigmf(go), A6);
            int oidx = (nb * BROWS + row) * HIDD + hcol;
            float cv = cx[oidx];
            float gated = qpact(cv * fg, A7);
            float actin = qpact(ig * act, A8);
            float ncv = qpact(gated + actin, A9);
            float acv = qpact(tanhf(ncv), A10);
            float nhv = qpact(acv * og, A11);
            out_h[oidx] = nhv;
            out_c[oidx] = ncv;
        }
    }
}

extern "C" void kernel_launch(void* const* d_in, const int* in_sizes, int n_in,
                              void* d_out, int out_size, void* d_ws, size_t ws_size,
                              hipStream_t stream) {
    const float* input = (const float*)d_in[0];
    const float* hx    = (const float*)d_in[1];
    const float* cx    = (const float*)d_in[2];
    const float* w_ih  = (const float*)d_in[3];
    const float* w_hh  = (const float*)d_in[4];
    const float* b_ih  = (const float*)d_in[5];
    const float* b_hh  = (const float*)d_in[6];
    const float* n_wih = (const float*)d_in[7];
    const float* n_whh = (const float*)d_in[8];
    const float* n_bih = (const float*)d_in[9];
    const float* n_bhh = (const float*)d_in[10];
    const float* a1  = (const float*)d_in[11];
    const float* a3  = (const float*)d_in[12];
    const float* a4  = (const float*)d_in[13];
    const float* a5  = (const float*)d_in[14];
    const float* a6  = (const float*)d_in[15];
    const float* a7  = (const float*)d_in[16];
    const float* a8  = (const float*)d_in[17];
    const float* a9  = (const float*)d_in[18];
    const float* a10 = (const float*)d_in[19];
    const float* a11 = (const float*)d_in[20];

    float* out_h = (float*)d_out;
    float* out_c = out_h + NBATCH * BROWS * HIDD;

    char* ws = (char*)d_ws;
    unsigned* maxes = (unsigned*)ws;
    __hip_bfloat16* xqh = (__hip_bfloat16*)(ws + 256);
    __hip_bfloat16* hxh = (__hip_bfloat16*)(ws + 256 + 2097152);
    __hip_bfloat16* hxl = (__hip_bfloat16*)(ws + 256 + 2 * 2097152);
    float* bias_comb    = (float*)(ws + 256 + 3 * 2097152);

    hipMemsetAsync(maxes, 0, 16, stream);
    k_max<<<dim3(256, 4), 256, 0, stream>>>(w_ih, w_hh, b_ih, b_hh, maxes);
    k_prep<<<2048, 256, 0, stream>>>(input, hx, b_ih, b_hh, n_bih, n_bhh, a1, maxes,
                                     xqh, hxh, hxl, bias_comb);
    k_gemm<<<NBATCH * 32, 1024, 0, stream>>>(w_ih, w_hh, n_wih, n_whh, xqh, hxh, hxl,
                                             bias_comb, cx,
                                             a3, a4, a5, a6, a7, a8, a9, a10, a11,
                                             maxes, out_h, out_c);
}